// Round 2
// baseline (260.402 us; speedup 1.0000x reference)
//
#include <hip/hip_runtime.h>

typedef __attribute__((ext_vector_type(8))) __bf16 bf16x8;
typedef __attribute__((ext_vector_type(4))) float f32x4;

#define LOG2E 1.4426950408889634f

// ---- workspace byte offsets ----
// NOTE: PART/L alias the Xt region (Xt is dead after k_conv3; stream-serial).
#define XT_OFF   0ul          // Xt  : bf16 [8][4096][256]  (x transposed, p-major)
#define PART_OFF 0ul          // PART: f32  [8][64][2048] column-sum partials (aliases Xt)
#define L_OFF    4194304ul    // L   : f32  [8][2048] log2 of softmax denominators
#define TT_OFF   16777216ul   // Tt  : bf16 [8][2048][256]  (x_theta, n-major)
#define PT_OFF   25165824ul   // Pt  : bf16 [8][2048][256]  (x_phi, n-major)
#define G_OFF    33554432ul   // G   : bf16 [8][256][2048]  (x_g, c-major)
#define OT_OFF   41943040ul   // OT  : bf16 [8][4096][128]  (out_nl transposed, p-major)
#define W3_OFF   50331648ul   // W3  : bf16 [384][256] (theta/phi/g weights stacked)
#define WM_OFF   50528256ul   // Wm  : bf16 [256][128]
#define WS_NEED  50593792ul

// ---------------- weights cast ----------------
__global__ __launch_bounds__(256) void k_weights(const float* wt, const float* wp,
                                                 const float* wg, const float* wm,
                                                 __bf16* W3, __bf16* Wm){
  int idx = blockIdx.x*256 + threadIdx.x;
  if (idx < 98304){
    float v = (idx < 32768) ? wt[idx] : (idx < 65536) ? wp[idx - 32768] : wg[idx - 65536];
    W3[idx] = (__bf16)v;
  } else if (idx < 131072){
    Wm[idx - 98304] = (__bf16)wm[idx - 98304];
  }
}

// ---------------- transpose+cast x: (b,256,4096) f32 -> Xt (b,4096,256) bf16 ----------------
__global__ __launch_bounds__(256) void k_xt(const float* x, __bf16* Xt){
  __shared__ float tile[64][65];
  int b = blockIdx.z, c0 = blockIdx.y*64, p0 = blockIdx.x*64;
  int t = threadIdx.x, col = t & 63, r0 = t >> 6;
  const float* xb = x + ((size_t)b*256 + c0)*4096 + p0;
  #pragma unroll
  for (int rr = 0; rr < 16; ++rr){
    int row = rr*4 + r0;
    tile[row][col] = xb[(size_t)row*4096 + col];
  }
  __syncthreads();
  __bf16* xo = Xt + ((size_t)b*4096 + p0)*256 + c0;
  #pragma unroll
  for (int rr = 0; rr < 16; ++rr){
    int prow = rr*4 + r0;
    xo[(size_t)prow*256 + col] = (__bf16)tile[col][prow];
  }
}

// ---------------- conv3: Xt(4096x256) * W3^T(384x256) -> theta/phi/g in attn layouts ----------------
__global__ __launch_bounds__(256) void k_conv3(const __bf16* Xt, const __bf16* W3,
                                               __bf16* Tt, __bf16* Pt, __bf16* G){
  __shared__ __bf16 As[128*72];
  __shared__ __bf16 Bs[64*72];
  int b = blockIdx.z, p0 = blockIdx.x*128, o0 = blockIdx.y*64;
  int tid = threadIdx.x, lane = tid & 63, wave = tid >> 6;
  int wm = wave >> 1, wn = wave & 1;
  f32x4 acc[4][2] = {};
  const __bf16* Ab = Xt + ((size_t)b*4096 + p0)*256;
  const __bf16* Bb = W3 + (size_t)o0*256;
  for (int kc = 0; kc < 4; ++kc){
    int k0 = kc*64;
    #pragma unroll
    for (int it = 0; it < 4; ++it){
      int s = tid + it*256, row = s >> 3, sk = s & 7;
      *(uint4*)&As[row*72 + sk*8] = *(const uint4*)(Ab + (size_t)row*256 + k0 + sk*8);
    }
    #pragma unroll
    for (int it = 0; it < 2; ++it){
      int s = tid + it*256, row = s >> 3, sk = s & 7;
      *(uint4*)&Bs[row*72 + sk*8] = *(const uint4*)(Bb + (size_t)row*256 + k0 + sk*8);
    }
    __syncthreads();
    #pragma unroll
    for (int ks = 0; ks < 2; ++ks){
      int koff = ks*32 + (lane>>4)*8;
      bf16x8 af[4], bfr[2];
      #pragma unroll
      for (int fm = 0; fm < 4; ++fm)
        af[fm] = *(const bf16x8*)&As[(wm*64 + fm*16 + (lane&15))*72 + koff];
      #pragma unroll
      for (int fn = 0; fn < 2; ++fn)
        bfr[fn] = *(const bf16x8*)&Bs[(wn*32 + fn*16 + (lane&15))*72 + koff];
      #pragma unroll
      for (int fm = 0; fm < 4; ++fm)
        #pragma unroll
        for (int fn = 0; fn < 2; ++fn)
          acc[fm][fn] = __builtin_amdgcn_mfma_f32_16x16x32_bf16(af[fm], bfr[fn], acc[fm][fn], 0, 0, 0);
    }
    __syncthreads();
  }
  // scatter per the reshape-view: flat = o*4096+p -> c = 2o+(p>>11), n = p&2047
  #pragma unroll
  for (int fm = 0; fm < 4; ++fm)
    #pragma unroll
    for (int fn = 0; fn < 2; ++fn)
      #pragma unroll
      for (int r = 0; r < 4; ++r){
        int p = p0 + wm*64 + fm*16 + (lane>>4)*4 + r;
        int o = o0 + wn*32 + fn*16 + (lane&15);
        __bf16 v = (__bf16)acc[fm][fn][r];
        int i = p & 2047, ph = p >> 11;
        if (o < 128)      Tt[((size_t)b*2048 + i)*256 + 2*o + ph] = v;
        else if (o < 256) Pt[((size_t)b*2048 + i)*256 + 2*(o-128) + ph] = v;
        else              G [((size_t)b*256 + 2*(o-256) + ph)*2048 + i] = v;
      }
}

// ---------------- pass A: column sums of exp(s) -> PART ----------------
// 256 thr / 4 waves, i-tile 32, Q hoisted in regs, B-frags from L2, no barriers.
__global__ __launch_bounds__(256, 2) void k_colsum(const __bf16* Tt, const __bf16* Pt, float* PART){
  int bid = blockIdx.x;
  int b = bid & 7, it = bid >> 3, i0 = it*32;   // batch -> XCD (wgid%8)
  int tid = threadIdx.x, lane = tid & 63, w = tid >> 6;
  int lr = lane & 15, kq = lane >> 4;
  int jl = w*16 + lr;
  const __bf16* Tb = Tt + ((size_t)b*2048 + i0)*256;
  const __bf16* Pb = Pt + (size_t)b*2048*256;
  bf16x8 q[2][8];
  #pragma unroll
  for (int fm = 0; fm < 2; ++fm)
    #pragma unroll
    for (int ks = 0; ks < 8; ++ks)
      q[fm][ks] = *(const bf16x8*)(Tb + (size_t)(fm*16 + lr)*256 + ks*32 + kq*8);
  for (int ch = 0; ch < 32; ++ch){
    int j0 = ch*64;
    const __bf16* pr = Pb + (size_t)(j0 + jl)*256 + kq*8;
    bf16x8 bq[8];
    #pragma unroll
    for (int ks = 0; ks < 8; ++ks) bq[ks] = *(const bf16x8*)(pr + ks*32);
    f32x4 sa[2] = {};
    #pragma unroll
    for (int ks = 0; ks < 8; ++ks){
      sa[0] = __builtin_amdgcn_mfma_f32_16x16x32_bf16(q[0][ks], bq[ks], sa[0], 0, 0, 0);
      sa[1] = __builtin_amdgcn_mfma_f32_16x16x32_bf16(q[1][ks], bq[ks], sa[1], 0, 0, 0);
    }
    float v = 0.f;
    #pragma unroll
    for (int fm = 0; fm < 2; ++fm)
      #pragma unroll
      for (int r = 0; r < 4; ++r)
        v += exp2f(sa[fm][r] * LOG2E);
    v += __shfl_xor(v, 16);
    v += __shfl_xor(v, 32);
    if (kq == 0) PART[((size_t)b*64 + it)*2048 + j0 + jl] = v;
  }
}

// ---------------- reduce partials -> L = log2(D) ----------------
__global__ __launch_bounds__(256) void k_logd(const float* PART, float* L){
  int idx = blockIdx.x*256 + threadIdx.x;   // 16384
  int b = idx >> 11, j = idx & 2047;
  float s = 0.f;
  #pragma unroll
  for (int it = 0; it < 64; ++it) s += PART[((size_t)b*64 + it)*2048 + j];
  L[idx] = log2f(s);
}

// ---------------- pass B: recompute s, w=exp2(s*log2e - L), out = w @ g ----------------
// 256 thr / 4 waves, i-tile 32, Q hoisted, double-buffered Ss, 1 barrier/chunk.
__global__ __launch_bounds__(256, 2) void k_attn(const __bf16* Tt, const __bf16* Pt,
                                                 const __bf16* G, const float* L, __bf16* OT){
  __shared__ __bf16 Ss[2][32*72];
  int bid = blockIdx.x;
  int b = bid & 7, it = bid >> 3, i0 = it*32;   // batch -> XCD (wgid%8)
  int tid = threadIdx.x, lane = tid & 63, w = tid >> 6;
  int lr = lane & 15, kq = lane >> 4;
  int jl = w*16 + lr;
  const __bf16* Tb = Tt + ((size_t)b*2048 + i0)*256;
  const __bf16* Pb = Pt + (size_t)b*2048*256;
  const __bf16* Gb = G + ((size_t)b*256 + w*64)*2048;
  const float*  Lb = L + (size_t)b*2048;
  // hoist Q fragments (16 x bf16x8 = 64 VGPR)
  bf16x8 q[2][8];
  #pragma unroll
  for (int fm = 0; fm < 2; ++fm)
    #pragma unroll
    for (int ks = 0; ks < 8; ++ks)
      q[fm][ks] = *(const bf16x8*)(Tb + (size_t)(fm*16 + lr)*256 + ks*32 + kq*8);
  f32x4 acc[2][4] = {};
  for (int ch = 0; ch < 32; ++ch){
    int j0 = ch*64;
    float Lv = Lb[j0 + jl];
    // QK: B-frags straight from L2
    const __bf16* pr = Pb + (size_t)(j0 + jl)*256 + kq*8;
    bf16x8 bq[8];
    #pragma unroll
    for (int ks = 0; ks < 8; ++ks) bq[ks] = *(const bf16x8*)(pr + ks*32);
    f32x4 sa[2] = {};
    #pragma unroll
    for (int ks = 0; ks < 8; ++ks){
      sa[0] = __builtin_amdgcn_mfma_f32_16x16x32_bf16(q[0][ks], bq[ks], sa[0], 0, 0, 0);
      sa[1] = __builtin_amdgcn_mfma_f32_16x16x32_bf16(q[1][ks], bq[ks], sa[1], 0, 0, 0);
    }
    // softmax weights -> Ss (double-buffered)
    __bf16* ss = &Ss[ch & 1][0];
    #pragma unroll
    for (int fm = 0; fm < 2; ++fm)
      #pragma unroll
      for (int r = 0; r < 4; ++r){
        float wgt = exp2f(__builtin_fmaf(sa[fm][r], LOG2E, -Lv));
        ss[(fm*16 + kq*4 + r)*72 + jl] = (__bf16)wgt;
      }
    __syncthreads();
    // PV: A from Ss (LDS), B = G rows from L2
    const __bf16* sb = &Ss[ch & 1][0];
    bf16x8 pa[2][2];
    #pragma unroll
    for (int fm = 0; fm < 2; ++fm)
      #pragma unroll
      for (int k2 = 0; k2 < 2; ++k2)
        pa[fm][k2] = *(const bf16x8*)&sb[(fm*16 + lr)*72 + k2*32 + kq*8];
    bf16x8 gv[4][2];
    #pragma unroll
    for (int fn = 0; fn < 4; ++fn)
      #pragma unroll
      for (int k2 = 0; k2 < 2; ++k2)
        gv[fn][k2] = *(const bf16x8*)(Gb + (size_t)(fn*16 + lr)*2048 + j0 + k2*32 + kq*8);
    #pragma unroll
    for (int fn = 0; fn < 4; ++fn)
      #pragma unroll
      for (int k2 = 0; k2 < 2; ++k2)
        #pragma unroll
        for (int fm = 0; fm < 2; ++fm)
          acc[fm][fn] = __builtin_amdgcn_mfma_f32_16x16x32_bf16(pa[fm][k2], gv[fn][k2], acc[fm][fn], 0, 0, 0);
  }
  // epilogue: out[i][c'] -> OT[p][ic] with ic=c'>>1, p=(c'&1)*2048+i
  #pragma unroll
  for (int fm = 0; fm < 2; ++fm)
    #pragma unroll
    for (int fn = 0; fn < 4; ++fn)
      #pragma unroll
      for (int r = 0; r < 4; ++r){
        int i = i0 + fm*16 + kq*4 + r;
        int cp = w*64 + fn*16 + lr;
        int p = ((cp & 1) << 11) + i;
        OT[((size_t)b*4096 + p)*128 + (cp >> 1)] = (__bf16)acc[fm][fn][r];
      }
}

// ---------------- mask conv + residual: OT(4096x128) * Wm^T(256x128) + x ----------------
__global__ __launch_bounds__(256) void k_mask(const __bf16* OT, const __bf16* Wm,
                                              const float* x, float* out){
  __shared__ __bf16 As[128*72];
  __shared__ __bf16 Bs[64*72];
  int b = blockIdx.z, p0 = blockIdx.x*128, o0 = blockIdx.y*64;
  int tid = threadIdx.x, lane = tid & 63, wave = tid >> 6;
  int wm = wave >> 1, wn = wave & 1;
  f32x4 acc[4][2] = {};
  const __bf16* Ab = OT + ((size_t)b*4096 + p0)*128;
  const __bf16* Bb = Wm + (size_t)o0*128;
  for (int kc = 0; kc < 2; ++kc){
    int k0 = kc*64;
    #pragma unroll
    for (int itc = 0; itc < 4; ++itc){
      int s = tid + itc*256, row = s >> 3, sk = s & 7;
      *(uint4*)&As[row*72 + sk*8] = *(const uint4*)(Ab + (size_t)row*128 + k0 + sk*8);
    }
    #pragma unroll
    for (int itc = 0; itc < 2; ++itc){
      int s = tid + itc*256, row = s >> 3, sk = s & 7;
      *(uint4*)&Bs[row*72 + sk*8] = *(const uint4*)(Bb + (size_t)row*128 + k0 + sk*8);
    }
    __syncthreads();
    #pragma unroll
    for (int ks = 0; ks < 2; ++ks){
      int koff = ks*32 + (lane>>4)*8;
      bf16x8 af[4], bfr[2];
      #pragma unroll
      for (int fm = 0; fm < 4; ++fm)
        af[fm] = *(const bf16x8*)&As[(wm*64 + fm*16 + (lane&15))*72 + koff];
      #pragma unroll
      for (int fn = 0; fn < 2; ++fn)
        bfr[fn] = *(const bf16x8*)&Bs[(wn*32 + fn*16 + (lane&15))*72 + koff];
      #pragma unroll
      for (int fm = 0; fm < 4; ++fm)
        #pragma unroll
        for (int fn = 0; fn < 2; ++fn)
          acc[fm][fn] = __builtin_amdgcn_mfma_f32_16x16x32_bf16(af[fm], bfr[fn], acc[fm][fn], 0, 0, 0);
    }
    __syncthreads();
  }
  #pragma unroll
  for (int fm = 0; fm < 4; ++fm)
    #pragma unroll
    for (int fn = 0; fn < 2; ++fn){
      int pb = p0 + wm*64 + fm*16 + (lane>>4)*4;
      int o = o0 + wn*32 + fn*16 + (lane&15);
      size_t idx = ((size_t)b*256 + o)*4096 + pb;
      f32x4 xv = *(const f32x4*)(x + idx);
      f32x4 ov = acc[fm][fn] + xv;
      *(f32x4*)(out + idx) = ov;
    }
}

extern "C" void kernel_launch(void* const* d_in, const int* in_sizes, int n_in,
                              void* d_out, int out_size, void* d_ws, size_t ws_size,
                              hipStream_t stream){
  if (ws_size < WS_NEED) return;  // workspace too small; fail visibly
  const float* x  = (const float*)d_in[0];
  const float* wt = (const float*)d_in[1];
  const float* wp = (const float*)d_in[2];
  const float* wg = (const float*)d_in[3];
  const float* wm = (const float*)d_in[4];
  char* ws = (char*)d_ws;
  __bf16* Xt  = (__bf16*)(ws + XT_OFF);
  __bf16* Tt  = (__bf16*)(ws + TT_OFF);
  __bf16* Pt  = (__bf16*)(ws + PT_OFF);
  __bf16* G   = (__bf16*)(ws + G_OFF);
  __bf16* OT  = (__bf16*)(ws + OT_OFF);
  __bf16* W3  = (__bf16*)(ws + W3_OFF);
  __bf16* Wm  = (__bf16*)(ws + WM_OFF);
  float* PART = (float*)(ws + PART_OFF);   // aliases Xt (dead after k_conv3)
  float* L    = (float*)(ws + L_OFF);
  float* out  = (float*)d_out;

  k_weights<<<512, 256, 0, stream>>>(wt, wp, wg, wm, W3, Wm);
  k_xt<<<dim3(64, 4, 8), 256, 0, stream>>>(x, Xt);
  k_conv3<<<dim3(32, 6, 8), 256, 0, stream>>>(Xt, W3, Tt, Pt, G);
  k_colsum<<<512, 256, 0, stream>>>(Tt, Pt, PART);
  k_logd<<<64, 256, 0, stream>>>(PART, L);
  k_attn<<<512, 256, 0, stream>>>(Tt, Pt, G, L, OT);
  k_mask<<<dim3(32, 4, 8), 256, 0, stream>>>(OT, Wm, x, out);
}